// Round 5
// baseline (1829.478 us; speedup 1.0000x reference)
//
#include <hip/hip_runtime.h>
#include <hip/hip_fp16.h>

#define Tn 1024
#define NB 128

// sigmoid(x) = 1/(1+exp2(S_RZ*x)); tanh(u): e=exp2(S_N*u), n=(1-e)/(1+e)
#define S_RZ (-1.4426950408889634f)
#define S_N  (-2.8853900817779268f)

typedef _Float16 h2_t  __attribute__((ext_vector_type(2)));
typedef _Float16 f16x8 __attribute__((ext_vector_type(8)));

__device__ __forceinline__ float dot2f(h2_t a, h2_t b, float c) {
#if __has_builtin(__builtin_amdgcn_fdot2)
  return __builtin_amdgcn_fdot2(a, b, c, false);
#else
  return c + (float)a[0] * (float)b[0] + (float)a[1] * (float)b[1];
#endif
}

__device__ __forceinline__ h2_t u2h(unsigned u) {
  union { unsigned u; h2_t h; } c; c.u = u; return c.h;
}

// ---- Phase 1: gv[d][v][row]: rows 0..511 = S_RZ*(gi+bhh) (r,z); rows 512..767 = S_N*gi (n)
__global__ __launch_bounds__(768)
void gv_build(const float* __restrict__ emb,
              const float* __restrict__ wihf, const float* __restrict__ bihf, const float* __restrict__ bhhf,
              const float* __restrict__ wihb, const float* __restrict__ bihb, const float* __restrict__ bhhb,
              float* __restrict__ gv)
{
  const int d  = blockIdx.x >> 7;
  const int v4 = (blockIdx.x & 127) * 4;
  const float* wih = d ? wihb : wihf;
  const float* bih = d ? bihb : bihf;
  const float* bhh = d ? bhhb : bhhf;
  __shared__ float se[4][128];
  const int tid = threadIdx.x;
  if (tid < 512) se[tid >> 7][tid & 127] = emb[(v4 + (tid >> 7)) * 128 + (tid & 127)];
  __syncthreads();
  const int row = tid;
  const float b0 = bih[row];
  float a0 = b0, a1 = b0, a2 = b0, a3 = b0;
  #pragma unroll
  for (int e = 0; e < 128; e += 4) {
    const float4 w = *reinterpret_cast<const float4*>(&wih[row * 128 + e]);
    a0 = fmaf(w.x, se[0][e], a0); a0 = fmaf(w.y, se[0][e+1], a0);
    a0 = fmaf(w.z, se[0][e+2], a0); a0 = fmaf(w.w, se[0][e+3], a0);
    a1 = fmaf(w.x, se[1][e], a1); a1 = fmaf(w.y, se[1][e+1], a1);
    a1 = fmaf(w.z, se[1][e+2], a1); a1 = fmaf(w.w, se[1][e+3], a1);
    a2 = fmaf(w.x, se[2][e], a2); a2 = fmaf(w.y, se[2][e+1], a2);
    a2 = fmaf(w.z, se[2][e+2], a2); a2 = fmaf(w.w, se[2][e+3], a2);
    a3 = fmaf(w.x, se[3][e], a3); a3 = fmaf(w.y, se[3][e+1], a3);
    a3 = fmaf(w.z, se[3][e+2], a3); a3 = fmaf(w.w, se[3][e+3], a3);
  }
  const float sc  = (row < 512) ? S_RZ : S_N;
  const float add = (row < 512) ? bhh[row] : 0.f;
  float* out = gv + (size_t)(d * 512 + v4) * 768 + row;
  out[0]    = sc * (a0 + add);
  out[768]  = sc * (a1 + add);
  out[1536] = sc * (a2 + add);
  out[2304] = sc * (a3 + add);
}

// 48 named f16x8 weight registers (192 VGPRs) -- no arrays, pure SSA values.
#define DW(i) f16x8 WR##i, WZ##i, WN##i;
#define PKG(G, SC, i) { \
  const float4 _a = *reinterpret_cast<const float4*>(row##G + 8 * i); \
  const float4 _c = *reinterpret_cast<const float4*>(row##G + 8 * i + 4); \
  W##G##i[0] = (_Float16)(_a.x * (SC)); W##G##i[1] = (_Float16)(_a.y * (SC)); \
  W##G##i[2] = (_Float16)(_a.z * (SC)); W##G##i[3] = (_Float16)(_a.w * (SC)); \
  W##G##i[4] = (_Float16)(_c.x * (SC)); W##G##i[5] = (_Float16)(_c.y * (SC)); \
  W##G##i[6] = (_Float16)(_c.z * (SC)); W##G##i[7] = (_Float16)(_c.w * (SC)); }
#define PK3(i) PKG(R, S_RZ, i) PKG(Z, S_RZ, i) PKG(N, S_N, i)
#define SL(v, a, b) (__builtin_shufflevector(v, v, a, b))
#define DOT(i) { \
  const uint4 _hq = *reinterpret_cast<const uint4*>(hrow + 16 * i); \
  const h2_t _h0 = u2h(_hq.x), _h1 = u2h(_hq.y), _h2 = u2h(_hq.z), _h3 = u2h(_hq.w); \
  ar = dot2f(SL(WR##i,0,1), _h0, ar); az = dot2f(SL(WZ##i,0,1), _h0, az); an = dot2f(SL(WN##i,0,1), _h0, an); \
  ar = dot2f(SL(WR##i,2,3), _h1, ar); az = dot2f(SL(WZ##i,2,3), _h1, az); an = dot2f(SL(WN##i,2,3), _h1, an); \
  ar = dot2f(SL(WR##i,4,5), _h2, ar); az = dot2f(SL(WZ##i,4,5), _h2, az); an = dot2f(SL(WN##i,4,5), _h2, an); \
  ar = dot2f(SL(WR##i,6,7), _h3, ar); az = dot2f(SL(WZ##i,6,7), _h3, az); an = dot2f(SL(WN##i,6,7), _h3, an); }

// ---- Phase 2: per-(batch,dir) GRU scan. 512 threads = 8 waves (2/SIMD, 256-reg cap).
// Thread (j=tid>>1, half=tid&1): gate rows {j, j+256, j+512}, k in [128*half, 128*half+128).
// half0 lanes: gv gather + h-update. half1 lanes: lagged emission partials (overlap).
__global__ __launch_bounds__(512, 2)
void gru_scan(const int* __restrict__ x,
              const float* __restrict__ gv,
              const float* __restrict__ whhf,
              const float* __restrict__ whhb,
              const float* __restrict__ bhhf,
              const float* __restrict__ bhhb,
              const float* __restrict__ fcw,
              float* __restrict__ em)
{
  const int tid  = threadIdx.x;
  const int j    = tid >> 1;
  const int half = tid & 1;
  const int dir  = blockIdx.x & 1;
  const int b    = blockIdx.x >> 1;

  const float* whh = dir ? whhb : whhf;
  const float* bhh = dir ? bhhb : bhhf;

  __shared__ __align__(16) char hls[2 * 544];  // h f16 dbl-buf; halves at +0 / +272 per buffer
  __shared__ float els[2][8];                  // emission partial exchange

  if (tid < 68) reinterpret_cast<uint4*>(hls)[tid] = make_uint4(0, 0, 0, 0);

  // ---- weight load: 48 named f16x8, scales folded in
  DW(0) DW(1) DW(2) DW(3) DW(4) DW(5) DW(6) DW(7)
  DW(8) DW(9) DW(10) DW(11) DW(12) DW(13) DW(14) DW(15)
  {
    const float* rowR = whh + (size_t)j * 256 + half * 128;
    const float* rowZ = rowR + 256 * 256;
    const float* rowN = rowZ + 256 * 256;
    PK3(0) PK3(1) PK3(2) PK3(3)
    __builtin_amdgcn_sched_barrier(0);
    PK3(4) PK3(5) PK3(6) PK3(7)
    __builtin_amdgcn_sched_barrier(0);
    PK3(8) PK3(9) PK3(10) PK3(11)
    __builtin_amdgcn_sched_barrier(0);
    PK3(12) PK3(13) PK3(14) PK3(15)
    __builtin_amdgcn_sched_barrier(0);
  }

  // n-gate bias: each half contributes 0.5*S_N*bhh_n via accumulator init
  const float bn2 = 0.5f * S_N * bhh[512 + j];

  // emission fc fragment (half1 lanes): wave w8 -> (label = w8&3, k-half = w8>>2)
  const int w8 = tid >> 6;
  const int kh = w8 >> 2;
  const int p  = (tid & 63) >> 1;
  h2_t fe0, fe1;
  {
    const float4 f = *reinterpret_cast<const float4*>(
        fcw + (w8 & 3) * 512 + dir * 256 + kh * 128 + 4 * p);
    fe0[0] = (_Float16)f.x; fe0[1] = (_Float16)f.y;
    fe1[0] = (_Float16)f.z; fe1[1] = (_Float16)f.w;
  }
  const int kh_off = kh * 272 + 8 * p;      // emission h2x2 read offset
  const int hr_off = half * 272;            // dot-phase h read offset
  const int hw_off = (j >> 7) * 272 + (j & 127) * 2;  // h write offset

  const float* gvd = gv + (size_t)dir * (512 * 768);
  const int*   xb  = x + b * Tn;
  float*       emo = em + (size_t)(dir * NB + b) * (Tn * 4);

  float ho = 0.f;
  int tok = xb[dir ? (Tn - 1) : 0];
  __syncthreads();

  for (int t = 0; t < Tn; ++t) {
    const int cur = t & 1;

    // gv gather (half0) + next-token prefetch: issued early, consumed late
    float gir = 0.f, giz = 0.f, gin = 0.f;
    if (!half) {
      const float* g = gvd + (size_t)tok * 768 + j;
      gir = g[0]; giz = g[256]; gin = g[512];
    }
    const int ntok = xb[dir ? (t + 2 <= Tn ? Tn - 2 - t : 0)
                           : (t + 1 < Tn ? t + 1 : 0)];

    // combine previous step's emission partials (4 half0 lanes)
    if (t >= 2 && tid < 4) {
      const float v = els[cur ^ 1][tid] + els[cur ^ 1][tid + 4];
      const int ptt = dir ? (Tn - (t - 1)) : (t - 2);
      emo[ptt * 4 + tid] = v;
    }

    // recurrent dots: 192 dot2 over named regs
    const char* hrow = hls + cur * 544 + hr_off;
    float ar = 0.f, az = 0.f, an = bn2;
    DOT(0) DOT(1) DOT(2) DOT(3)
    __builtin_amdgcn_sched_barrier(0);
    DOT(4) DOT(5) DOT(6) DOT(7)
    __builtin_amdgcn_sched_barrier(0);
    DOT(8) DOT(9) DOT(10) DOT(11)
    __builtin_amdgcn_sched_barrier(0);
    DOT(12) DOT(13) DOT(14) DOT(15)

    // combine halves (adjacent lanes)
    ar += __shfl_xor(ar, 1);
    az += __shfl_xor(az, 1);
    an += __shfl_xor(an, 1);

    if (!half) {
      // pre-scaled exp2-form activations
      const float er = __builtin_amdgcn_exp2f(gir + ar);
      const float r  = __builtin_amdgcn_rcpf(1.f + er);
      const float ez = __builtin_amdgcn_exp2f(giz + az);
      const float z  = __builtin_amdgcn_rcpf(1.f + ez);
      float y = fmaf(r, an, gin);
      y = fminf(y, 126.f);
      const float en = __builtin_amdgcn_exp2f(y);
      const float n  = (1.f - en) * __builtin_amdgcn_rcpf(1.f + en);
      const float hnew = fmaf(z, ho - n, n);
      ho = hnew;
      *reinterpret_cast<_Float16*>(hls + (cur ^ 1) * 544 + hw_off) = (_Float16)hnew;
    } else if (t > 0) {
      // emission partials of h_{t-1} (hls[cur]); 2 dot2 + 5-level odd-lane reduce
      const uint2 hq = *reinterpret_cast<const uint2*>(hls + cur * 544 + kh_off);
      float pa = dot2f(fe0, u2h(hq.x), 0.f);
      pa = dot2f(fe1, u2h(hq.y), pa);
      pa += __shfl_xor(pa, 2);  pa += __shfl_xor(pa, 4);  pa += __shfl_xor(pa, 8);
      pa += __shfl_xor(pa, 16); pa += __shfl_xor(pa, 32);
      if ((tid & 63) == 1) els[t & 1][w8] = pa;
    }
    tok = ntok;
    __syncthreads();
  }

  // pending combine: partials from t=Tn-1 (h_{Tn-2})
  if (tid < 4) {
    const float v = els[1][tid] + els[1][tid + 4];
    emo[(dir ? 1 : (Tn - 2)) * 4 + tid] = v;
  }
  // final h_{Tn-1} lives in buffer 0
  if (half) {
    const uint2 hq = *reinterpret_cast<const uint2*>(hls + kh_off);
    float pa = dot2f(fe0, u2h(hq.x), 0.f);
    pa = dot2f(fe1, u2h(hq.y), pa);
    pa += __shfl_xor(pa, 2);  pa += __shfl_xor(pa, 4);  pa += __shfl_xor(pa, 8);
    pa += __shfl_xor(pa, 16); pa += __shfl_xor(pa, 32);
    if ((tid & 63) == 1) els[0][w8] = pa;
  }
  __syncthreads();
  if (tid < 4) {
    const float v = els[0][tid] + els[0][tid + 4];
    emo[(dir ? 0 : (Tn - 1)) * 4 + tid] = v;
  }
}

// ---- Phase 3: CRF negative log-likelihood per batch (4 lanes per batch element)
__global__ __launch_bounds__(64)
void crf_nllh(const int* __restrict__ tags,
              const float* __restrict__ em,
              const float* __restrict__ fc_b,
              const float* __restrict__ st,
              const float* __restrict__ et,
              const float* __restrict__ tr,
              float* __restrict__ llh)
{
  const int lane = threadIdx.x;
  const int l = lane & 3;
  const int q = lane >> 2;
  const int b = blockIdx.x * 16 + q;
  const float* ef = em + (size_t)b * Tn * 4;
  const float* eb = em + ((size_t)NB + b) * Tn * 4;
  const int* tg = tags + b * Tn;
  const float fcb = fc_b[l];
  const float tc0 = tr[l * 4 + l];
  const float tc1 = tr[(l ^ 1) * 4 + l];
  const float tc2 = tr[(l ^ 2) * 4 + l];
  const float tc3 = tr[(l ^ 3) * 4 + l];

  const float e0 = ef[l] + eb[l] + fcb;
  float alpha = st[l] + e0;
  int tprev = tg[0];
  float score = (tprev == l) ? (st[l] + e0) : 0.f;

  #pragma unroll 8
  for (int t = 1; t < Tn; ++t) {
    const float e = ef[t * 4 + l] + eb[t * 4 + l] + fcb;
    const int tc = tg[t];
    if (tc == l) {
      const int s2 = tprev ^ l;
      const float tsel = (s2 & 1) ? ((s2 & 2) ? tc3 : tc1)
                                  : ((s2 & 2) ? tc2 : tc0);
      score += e + tsel;
    }
    tprev = tc;
    const float a1 = __shfl_xor(alpha, 1);
    const float a2 = __shfl_xor(alpha, 2);
    const float a3 = __shfl_xor(alpha, 3);
    const float v0 = alpha + tc0;
    const float v1 = a1 + tc1;
    const float v2 = a2 + tc2;
    const float v3 = a3 + tc3;
    const float mx = fmaxf(fmaxf(v0, v1), fmaxf(v2, v3));
    const float s = __expf(v0 - mx) + __expf(v1 - mx) + __expf(v2 - mx) + __expf(v3 - mx);
    alpha = mx + __logf(s) + e;
  }

  score += (tprev == l) ? et[l] : 0.f;
  float ae = alpha + et[l];
  float m1 = fmaxf(ae, __shfl_xor(ae, 1));
  m1 = fmaxf(m1, __shfl_xor(m1, 2));
  float se = __expf(ae - m1);
  se += __shfl_xor(se, 1);
  se += __shfl_xor(se, 2);
  const float logZ = m1 + __logf(se);
  float sc = score + __shfl_xor(score, 1);
  sc += __shfl_xor(sc, 2);
  if (l == 0) llh[b] = sc - logZ;
}

// ---- Phase 4: out = -mean(llh)
__global__ __launch_bounds__(128)
void reduce_mean(const float* __restrict__ llh, float* __restrict__ out)
{
  const int t = threadIdx.x;
  float v = llh[t];
  #pragma unroll
  for (int m = 32; m >= 1; m >>= 1) v += __shfl_xor(v, m);
  __shared__ float s2[2];
  if ((t & 63) == 0) s2[t >> 6] = v;
  __syncthreads();
  if (t == 0) out[0] = -(s2[0] + s2[1]) * (1.f / 128.f);
}

extern "C" void kernel_launch(void* const* d_in, const int* in_sizes, int n_in,
                              void* d_out, int out_size, void* d_ws, size_t ws_size,
                              hipStream_t stream) {
  const int*   x    = (const int*)d_in[0];
  const int*   tags = (const int*)d_in[1];
  // d_in[2] = mask (all ones) -- unused
  const float* emb  = (const float*)d_in[3];
  const float* wihf = (const float*)d_in[4];
  const float* whhf = (const float*)d_in[5];
  const float* bihf = (const float*)d_in[6];
  const float* bhhf = (const float*)d_in[7];
  const float* wihb = (const float*)d_in[8];
  const float* whhb = (const float*)d_in[9];
  const float* bihb = (const float*)d_in[10];
  const float* bhhb = (const float*)d_in[11];
  const float* fcw  = (const float*)d_in[12];
  const float* fcb  = (const float*)d_in[13];
  const float* st   = (const float*)d_in[14];
  const float* et   = (const float*)d_in[15];
  const float* tr   = (const float*)d_in[16];

  char* ws = (char*)d_ws;
  float* gv  = (float*)ws;                          // 2*512*768*4   = 3,145,728 B
  float* em  = (float*)(ws + 3145728);              // 2*128*1024*4*4 = 4,194,304 B
  float* llh = (float*)(ws + 3145728 + 4194304);    // 512 B

  gv_build<<<dim3(256), dim3(768), 0, stream>>>(emb, wihf, bihf, bhhf, wihb, bihb, bhhb, gv);
  gru_scan<<<dim3(256), dim3(512), 0, stream>>>(x, gv, whhf, whhb, bhhf, bhhb, fcw, em);
  crf_nllh<<<dim3(8), dim3(64), 0, stream>>>(tags, em, fcb, st, et, tr, llh);
  reduce_mean<<<dim3(1), dim3(128), 0, stream>>>(llh, (float*)d_out);
}

// Round 7
// 1759.269 us; speedup vs baseline: 1.0399x; 1.0399x over previous
//
#include <hip/hip_runtime.h>
#include <hip/hip_fp16.h>

#define Tn 1024
#define NB 128

// sigmoid(x) = 1/(1+exp2(S_RZ*x)); tanh(u): e=exp2(S_N*u), n=(1-e)/(1+e)
#define S_RZ (-1.4426950408889634f)
#define S_N  (-2.8853900817779268f)

typedef _Float16 h2_t  __attribute__((ext_vector_type(2)));
typedef _Float16 f16x8 __attribute__((ext_vector_type(8)));
typedef float    f32x4 __attribute__((ext_vector_type(4)));

__device__ __forceinline__ float dot2f(h2_t a, h2_t b, float c) {
#if __has_builtin(__builtin_amdgcn_fdot2)
  return __builtin_amdgcn_fdot2(a, b, c, false);
#else
  return c + (float)a[0] * (float)b[0] + (float)a[1] * (float)b[1];
#endif
}

__device__ __forceinline__ h2_t u2h(unsigned u) {
  union { unsigned u; h2_t h; } c; c.u = u; return c.h;
}

template <int CTRL>
__device__ __forceinline__ float dppadd(float v) {
  int i = __builtin_bit_cast(int, v);
  int r = __builtin_amdgcn_update_dpp(i, i, CTRL, 0xF, 0xF, true);
  return v + __builtin_bit_cast(float, r);
}

// ---- Phase 1: packed token table, f32.
// gvp[d][v][ slot ], slot = ((w*2+tau)*3+g)*16 + c for hidden row j = w*32+tau*16+c:
//   g=0: S_RZ*(gi_r[j]+bhh_r[j]);  g=1: S_RZ*(gi_z[j]+bhh_z[j]);  g=2: S_N*gi_n[j]
__global__ __launch_bounds__(768)
void gv_build(const float* __restrict__ emb,
              const float* __restrict__ wihf, const float* __restrict__ bihf, const float* __restrict__ bhhf,
              const float* __restrict__ wihb, const float* __restrict__ bihb, const float* __restrict__ bhhb,
              float* __restrict__ gvp)
{
  const int d  = blockIdx.x >> 7;
  const int v4 = (blockIdx.x & 127) * 4;
  const float* wih = d ? wihb : wihf;
  const float* bih = d ? bihb : bihf;
  const float* bhh = d ? bhhb : bhhf;
  __shared__ float se[4][128];
  const int tid = threadIdx.x;
  if (tid < 512) se[tid >> 7][tid & 127] = emb[(v4 + (tid >> 7)) * 128 + (tid & 127)];
  __syncthreads();
  const int row = tid;
  const float b0 = bih[row];
  float a0 = b0, a1 = b0, a2 = b0, a3 = b0;
  #pragma unroll
  for (int e = 0; e < 128; e += 4) {
    const float4 w = *reinterpret_cast<const float4*>(&wih[row * 128 + e]);
    a0 = fmaf(w.x, se[0][e], a0); a0 = fmaf(w.y, se[0][e+1], a0);
    a0 = fmaf(w.z, se[0][e+2], a0); a0 = fmaf(w.w, se[0][e+3], a0);
    a1 = fmaf(w.x, se[1][e], a1); a1 = fmaf(w.y, se[1][e+1], a1);
    a1 = fmaf(w.z, se[1][e+2], a1); a1 = fmaf(w.w, se[1][e+3], a1);
    a2 = fmaf(w.x, se[2][e], a2); a2 = fmaf(w.y, se[2][e+1], a2);
    a2 = fmaf(w.z, se[2][e+2], a2); a2 = fmaf(w.w, se[2][e+3], a2);
    a3 = fmaf(w.x, se[3][e], a3); a3 = fmaf(w.y, se[3][e+1], a3);
    a3 = fmaf(w.z, se[3][e+2], a3); a3 = fmaf(w.w, se[3][e+3], a3);
  }
  const int g  = row >> 8, j = row & 255;
  const int w  = j >> 5, tu = (j >> 4) & 1, c = j & 15;
  const float sc  = (g == 2) ? S_N : S_RZ;
  const float add = (g < 2) ? bhh[row] : 0.f;
  const int slot = ((w * 2 + tu) * 3 + g) * 16 + c;
  float* out = gvp + (size_t)(d * 512 + v4) * 768 + slot;
  out[0]    = sc * (a0 + add);
  out[768]  = sc * (a1 + add);
  out[1536] = sc * (a2 + add);
  out[2304] = sc * (a3 + add);
}

// ---- Phase 2: per-(batch,dir) GRU scan via MFMA matvec.
// 512 thr = 8 waves, 2/SIMD. Wave w owns gate rows w*32..w*32+31 (x3 gates).
// B-frags = W^T (f16, scales folded) resident in AGPR-space; A = h replicated
// into all 16 rows (LDS broadcast reads). Lane c=l&15 gets gates for h-rows
// (w*32+c, w*32+16+c) in acc reg 0 -> 2-row update/lane, no exchange.
// gv staged LDS (wg-uniform token); emissions: distributed dot2 + DPP reduce.
__global__ __launch_bounds__(512, 2)
void gru_scan(const int* __restrict__ x,
              const float* __restrict__ gvp,
              const float* __restrict__ whhf,
              const float* __restrict__ whhb,
              const float* __restrict__ bhhf,
              const float* __restrict__ bhhb,
              const float* __restrict__ fcw,
              float* __restrict__ em)
{
  const int tid = threadIdx.x;
  const int w   = tid >> 6;
  const int l   = tid & 63;
  const int c   = l & 15;
  const int lg  = l >> 4;
  const int dir = blockIdx.x & 1;
  const int b   = blockIdx.x >> 1;

  const float* whh = dir ? whhb : whhf;
  const float* bhh = dir ? bhhb : bhhf;

  __shared__ __align__(16) _Float16 hls[2][256];  // h double-buffer (1 KB)
  __shared__ float gvs[2][768];                   // staged token table (6 KB)
  __shared__ float els[2][8];                     // emission partials

  if (tid < 64) reinterpret_cast<uint4*>(hls)[tid] = make_uint4(0, 0, 0, 0);

  // B-frags: bf[g][tau][ks]; lane: W[g*256 + w*32 + tau*16 + c][ks*32 + lg*8 + e]
  f16x8 bf[3][2][8];
  #pragma unroll
  for (int g = 0; g < 3; ++g) {
    const float sc = (g == 2) ? S_N : S_RZ;
    #pragma unroll
    for (int tu = 0; tu < 2; ++tu) {
      const float* wrow = whh + (size_t)(g * 256 + w * 32 + tu * 16 + c) * 256 + lg * 8;
      #pragma unroll
      for (int ks = 0; ks < 8; ++ks) {
        const float4 f0 = *reinterpret_cast<const float4*>(wrow + ks * 32);
        const float4 f1 = *reinterpret_cast<const float4*>(wrow + ks * 32 + 4);
        f16x8 v;
        v[0] = (_Float16)(f0.x * sc); v[1] = (_Float16)(f0.y * sc);
        v[2] = (_Float16)(f0.z * sc); v[3] = (_Float16)(f0.w * sc);
        v[4] = (_Float16)(f1.x * sc); v[5] = (_Float16)(f1.y * sc);
        v[6] = (_Float16)(f1.z * sc); v[7] = (_Float16)(f1.w * sc);
        bf[g][tu][ks] = v;
      }
    }
  }

  const float bn0 = S_N * bhh[512 + w * 32 + c];
  const float bn1 = S_N * bhh[512 + w * 32 + 16 + c];

  // emission fragment: label = tid>>7, k-pair = tid&127
  const int lab = tid >> 7;
  const int kp  = tid & 127;
  h2_t fce;
  fce[0] = (_Float16)fcw[lab * 512 + dir * 256 + 2 * kp];
  fce[1] = (_Float16)fcw[lab * 512 + dir * 256 + 2 * kp + 1];

  const int*   xb  = x + b * Tn;
  float*       emo = em + (size_t)(dir * NB + b) * (Tn * 4);
  const float* gvd = gvp + (size_t)dir * (512 * 768);

  // prologue: stage gv for step 0
  {
    const float* gr = gvd + (size_t)xb[dir ? (Tn - 1) : 0] * 768;
    gvs[0][tid] = gr[tid];
    if (tid < 256) gvs[0][tid + 512] = gr[tid + 512];
  }
  float ho0 = 0.f, ho1 = 0.f;
  __syncthreads();

  for (int t = 0; t < Tn; ++t) {
    const int cur = t & 1;

    // stage loads for step t+1 (issued early, LDS-written late)
    const int tn1 = (t + 1 < Tn) ? (t + 1) : (Tn - 1);
    const float* gr = gvd + (size_t)xb[dir ? (Tn - 1 - tn1) : tn1] * 768;
    const float su0 = gr[tid];
    const float su1 = (tid < 256) ? gr[tid + 512] : 0.f;

    // emission partial of h_{t-1} (hls[cur]); all-lane DPP/shfl reduce
    {
      const unsigned hq = *reinterpret_cast<const unsigned*>(&hls[cur][kp * 2]);
      float pa = dot2f(fce, u2h(hq), 0.f);
      pa = dppadd<0xB1>(pa);   // xor1
      pa = dppadd<0x4E>(pa);   // xor2
      pa = dppadd<0x141>(pa);  // half-mirror (=xor4 after quads uniform)
      pa = dppadd<0x140>(pa);  // mirror (=xor8)
      pa += __shfl_xor(pa, 16);
      pa += __shfl_xor(pa, 32);
      if (l == 0) els[cur][w] = pa;
    }
    // combine previous partials -> em[s = t-2]
    if (t >= 2 && tid < 4) {
      const float v = els[cur ^ 1][2 * tid] + els[cur ^ 1][2 * tid + 1];
      const int ptt = dir ? (Tn + 1 - t) : (t - 2);
      emo[ptt * 4 + tid] = v;
    }

    // acc init from staged gv (C reg0 = row lg*4, valid for every lane)
    const float* gc = gvs[cur] + w * 96 + c;
    f32x4 aR0 = {gc[0],  0.f, 0.f, 0.f};
    f32x4 aZ0 = {gc[16], 0.f, 0.f, 0.f};
    f32x4 aN0 = {bn0,    0.f, 0.f, 0.f};
    f32x4 aR1 = {gc[48], 0.f, 0.f, 0.f};
    f32x4 aZ1 = {gc[64], 0.f, 0.f, 0.f};
    f32x4 aN1 = {bn1,    0.f, 0.f, 0.f};
    const float gin0 = gc[32];
    const float gin1 = gc[80];

    // MFMA chain: A = h (replicated rows), B = resident W^T frags
    const _Float16* hc = hls[cur];
    #pragma unroll
    for (int ks = 0; ks < 4; ++ks) {
      const f16x8 a = *reinterpret_cast<const f16x8*>(hc + ks * 32 + lg * 8);
      aR0 = __builtin_amdgcn_mfma_f32_16x16x32_f16(a, bf[0][0][ks], aR0, 0, 0, 0);
      aZ0 = __builtin_amdgcn_mfma_f32_16x16x32_f16(a, bf[1][0][ks], aZ0, 0, 0, 0);
      aN0 = __builtin_amdgcn_mfma_f32_16x16x32_f16(a, bf[2][0][ks], aN0, 0, 0, 0);
      aR1 = __builtin_amdgcn_mfma_f32_16x16x32_f16(a, bf[0][1][ks], aR1, 0, 0, 0);
      aZ1 = __builtin_amdgcn_mfma_f32_16x16x32_f16(a, bf[1][1][ks], aZ1, 0, 0, 0);
      aN1 = __builtin_amdgcn_mfma_f32_16x16x32_f16(a, bf[2][1][ks], aN1, 0, 0, 0);
    }
    __builtin_amdgcn_sched_barrier(0);
    #pragma unroll
    for (int ks = 4; ks < 8; ++ks) {
      const f16x8 a = *reinterpret_cast<const f16x8*>(hc + ks * 32 + lg * 8);
      aR0 = __builtin_amdgcn_mfma_f32_16x16x32_f16(a, bf[0][0][ks], aR0, 0, 0, 0);
      aZ0 = __builtin_amdgcn_mfma_f32_16x16x32_f16(a, bf[1][0][ks], aZ0, 0, 0, 0);
      aN0 = __builtin_amdgcn_mfma_f32_16x16x32_f16(a, bf[2][0][ks], aN0, 0, 0, 0);
      aR1 = __builtin_amdgcn_mfma_f32_16x16x32_f16(a, bf[0][1][ks], aR1, 0, 0, 0);
      aZ1 = __builtin_amdgcn_mfma_f32_16x16x32_f16(a, bf[1][1][ks], aZ1, 0, 0, 0);
      aN1 = __builtin_amdgcn_mfma_f32_16x16x32_f16(a, bf[2][1][ks], aN1, 0, 0, 0);
    }

    // update: 2 rows per lane (tau=0,1), exp2-form activations
    {
      const float er0 = __builtin_amdgcn_exp2f(aR0[0]);
      const float rr0 = __builtin_amdgcn_rcpf(1.f + er0);
      const float ez0 = __builtin_amdgcn_exp2f(aZ0[0]);
      const float zz0 = __builtin_amdgcn_rcpf(1.f + ez0);
      float y0 = fmaf(rr0, aN0[0], gin0);
      y0 = fminf(y0, 126.f);
      const float en0 = __builtin_amdgcn_exp2f(y0);
      const float nn0 = (1.f - en0) * __builtin_amdgcn_rcpf(1.f + en0);
      const float h0 = fmaf(zz0, ho0 - nn0, nn0);

      const float er1 = __builtin_amdgcn_exp2f(aR1[0]);
      const float rr1 = __builtin_amdgcn_rcpf(1.f + er1);
      const float ez1 = __builtin_amdgcn_exp2f(aZ1[0]);
      const float zz1 = __builtin_amdgcn_rcpf(1.f + ez1);
      float y1 = fmaf(rr1, aN1[0], gin1);
      y1 = fminf(y1, 126.f);
      const float en1 = __builtin_amdgcn_exp2f(y1);
      const float nn1 = (1.f - en1) * __builtin_amdgcn_rcpf(1.f + en1);
      const float h1 = fmaf(zz1, ho1 - nn1, nn1);

      ho0 = h0; ho1 = h1;
      if (lg == 0) {
        hls[cur ^ 1][w * 32 + c]      = (_Float16)h0;
        hls[cur ^ 1][w * 32 + 16 + c] = (_Float16)h1;
      }
    }

    // staging LDS write for step t+1
    gvs[cur ^ 1][tid] = su0;
    if (tid < 256) gvs[cur ^ 1][tid + 512] = su1;
    __syncthreads();
  }

  // tail: em for s=Tn-2 (partials in els[1]) and s=Tn-1 (h in hls[0])
  if (tid < 4) {
    const float v = els[1][2 * tid] + els[1][2 * tid + 1];
    emo[(dir ? 1 : (Tn - 2)) * 4 + tid] = v;
  }
  {
    const unsigned hq = *reinterpret_cast<const unsigned*>(&hls[0][kp * 2]);
    float pa = dot2f(fce, u2h(hq), 0.f);
    pa = dppadd<0xB1>(pa);
    pa = dppadd<0x4E>(pa);
    pa = dppadd<0x141>(pa);
    pa = dppadd<0x140>(pa);
    pa += __shfl_xor(pa, 16);
    pa += __shfl_xor(pa, 32);
    if (l == 0) els[0][w] = pa;
  }
  __syncthreads();
  if (tid < 4) {
    const float v = els[0][2 * tid] + els[0][2 * tid + 1];
    emo[(dir ? 0 : (Tn - 1)) * 4 + tid] = v;
  }
}

// ---- Phase 3: CRF negative log-likelihood per batch (4 lanes per batch element)
__global__ __launch_bounds__(64)
void crf_nllh(const int* __restrict__ tags,
              const float* __restrict__ em,
              const float* __restrict__ fc_b,
              const float* __restrict__ st,
              const float* __restrict__ et,
              const float* __restrict__ tr,
              float* __restrict__ llh)
{
  const int lane = threadIdx.x;
  const int l = lane & 3;
  const int q = lane >> 2;
  const int b = blockIdx.x * 16 + q;
  const float* ef = em + (size_t)b * Tn * 4;
  const float* eb = em + ((size_t)NB + b) * Tn * 4;
  const int* tg = tags + b * Tn;
  const float fcb = fc_b[l];
  const float tc0 = tr[l * 4 + l];
  const float tc1 = tr[(l ^ 1) * 4 + l];
  const float tc2 = tr[(l ^ 2) * 4 + l];
  const float tc3 = tr[(l ^ 3) * 4 + l];

  const float e0 = ef[l] + eb[l] + fcb;
  float alpha = st[l] + e0;
  int tprev = tg[0];
  float score = (tprev == l) ? (st[l] + e0) : 0.f;

  #pragma unroll 8
  for (int t = 1; t < Tn; ++t) {
    const float e = ef[t * 4 + l] + eb[t * 4 + l] + fcb;
    const int tc = tg[t];
    if (tc == l) {
      const int s2 = tprev ^ l;
      const float tsel = (s2 & 1) ? ((s2 & 2) ? tc3 : tc1)
                                  : ((s2 & 2) ? tc2 : tc0);
      score += e + tsel;
    }
    tprev = tc;
    const float a1 = __shfl_xor(alpha, 1);
    const float a2 = __shfl_xor(alpha, 2);
    const float a3 = __shfl_xor(alpha, 3);
    const float v0 = alpha + tc0;
    const float v1 = a1 + tc1;
    const float v2 = a2 + tc2;
    const float v3 = a3 + tc3;
    const float mx = fmaxf(fmaxf(v0, v1), fmaxf(v2, v3));
    const float s = __expf(v0 - mx) + __expf(v1 - mx) + __expf(v2 - mx) + __expf(v3 - mx);
    alpha = mx + __logf(s) + e;
  }

  score += (tprev == l) ? et[l] : 0.f;
  float ae = alpha + et[l];
  float m1 = fmaxf(ae, __shfl_xor(ae, 1));
  m1 = fmaxf(m1, __shfl_xor(m1, 2));
  float se = __expf(ae - m1);
  se += __shfl_xor(se, 1);
  se += __shfl_xor(se, 2);
  const float logZ = m1 + __logf(se);
  float sc = score + __shfl_xor(score, 1);
  sc += __shfl_xor(sc, 2);
  if (l == 0) llh[b] = sc - logZ;
}

// ---- Phase 4: out = -mean(llh)
__global__ __launch_bounds__(128)
void reduce_mean(const float* __restrict__ llh, float* __restrict__ out)
{
  const int t = threadIdx.x;
  float v = llh[t];
  #pragma unroll
  for (int m = 32; m >= 1; m >>= 1) v += __shfl_xor(v, m);
  __shared__ float s2[2];
  if ((t & 63) == 0) s2[t >> 6] = v;
  __syncthreads();
  if (t == 0) out[0] = -(s2[0] + s2[1]) * (1.f / 128.f);
}

extern "C" void kernel_launch(void* const* d_in, const int* in_sizes, int n_in,
                              void* d_out, int out_size, void* d_ws, size_t ws_size,
                              hipStream_t stream) {
  const int*   x    = (const int*)d_in[0];
  const int*   tags = (const int*)d_in[1];
  // d_in[2] = mask (all ones) -- unused
  const float* emb  = (const float*)d_in[3];
  const float* wihf = (const float*)d_in[4];
  const float* whhf = (const float*)d_in[5];
  const float* bihf = (const float*)d_in[6];
  const float* bhhf = (const float*)d_in[7];
  const float* wihb = (const float*)d_in[8];
  const float* whhb = (const float*)d_in[9];
  const float* bihb = (const float*)d_in[10];
  const float* bhhb = (const float*)d_in[11];
  const float* fcw  = (const float*)d_in[12];
  const float* fcb  = (const float*)d_in[13];
  const float* st   = (const float*)d_in[14];
  const float* et   = (const float*)d_in[15];
  const float* tr   = (const float*)d_in[16];

  char* ws = (char*)d_ws;
  float* gvp = (float*)ws;                          // 2*512*768*4   = 3,145,728 B
  float* em  = (float*)(ws + 3145728);              // 2*128*1024*4*4 = 4,194,304 B
  float* llh = (float*)(ws + 3145728 + 4194304);    // 512 B

  gv_build<<<dim3(256), dim3(768), 0, stream>>>(emb, wihf, bihf, bhhf, wihb, bihb, bhhb, gvp);
  gru_scan<<<dim3(256), dim3(512), 0, stream>>>(x, gvp, whhf, whhb, bhhf, bhhb, fcw, em);
  crf_nllh<<<dim3(8), dim3(64), 0, stream>>>(tags, em, fcb, st, et, tr, llh);
  reduce_mean<<<dim3(1), dim3(128), 0, stream>>>(llh, (float*)d_out);
}